// Round 1
// baseline (737.037 us; speedup 1.0000x reference)
//
#include <hip/hip_runtime.h>

#define KF 128        // feature dim
#define NSUP 256      // support points per species
#define NSPEC 4
#define TA 64         // atom tile
#define TM 64         // support tile

// ---------------- species bucketing ----------------

__global__ void k_count(const int* __restrict__ sp, int n, int* __restrict__ counts) {
    __shared__ int h[NSPEC];
    if (threadIdx.x < NSPEC) h[threadIdx.x] = 0;
    __syncthreads();
    for (int i = blockIdx.x * blockDim.x + threadIdx.x; i < n; i += gridDim.x * blockDim.x)
        atomicAdd(&h[sp[i]], 1);
    __syncthreads();
    if (threadIdx.x < NSPEC) atomicAdd(&counts[threadIdx.x], h[threadIdx.x]);
}

__global__ void k_scan(int* ws) {
    // ws[0..3]=counts  ws[4..7]=offsets  ws[8..11]=cursors
    if (threadIdx.x == 0 && blockIdx.x == 0) {
        int acc = 0;
        for (int q = 0; q < NSPEC; ++q) { ws[4 + q] = acc; ws[8 + q] = acc; acc += ws[q]; }
    }
}

__global__ void k_scatter(const int* __restrict__ sp, int n,
                          int* __restrict__ cursors, int* __restrict__ order) {
    __shared__ int lh[NSPEC];
    __shared__ int base[NSPEC];
    if (threadIdx.x < NSPEC) lh[threadIdx.x] = 0;
    __syncthreads();
    int i = blockIdx.x * blockDim.x + threadIdx.x;
    int s = (i < n) ? sp[i] : -1;
    int local = 0;
    if (s >= 0) local = atomicAdd(&lh[s], 1);
    __syncthreads();
    if (threadIdx.x < NSPEC) base[threadIdx.x] = atomicAdd(&cursors[threadIdx.x], lh[threadIdx.x]);
    __syncthreads();
    if (s >= 0) order[base[s] + local] = i;
}

// ---------------- main fused kernel ----------------
// Per block: TA atoms (one species) x all 256 support vectors.
// LDS layout: row-major float4 [row][c], c XOR-swizzled by ((row>>2)&7) so the
// 4x4 register-tile b128 reads are broadcast / conflict-light.

__global__ __launch_bounds__(256, 2) void k_main(
    const float* __restrict__ ps,
    const float* __restrict__ support,
    const float* __restrict__ weights,
    const int* __restrict__ struct_ids,
    float* __restrict__ out,
    const int* __restrict__ counts,
    const int* __restrict__ offsets,
    const int* __restrict__ order)
{
    __shared__ float4 ldsA[TA * 32];   // 32 KB
    __shared__ float4 ldsS[TM * 32];   // 32 KB
    __shared__ float  lds_w[NSUP];
    __shared__ float  nrm[TA];
    __shared__ float  inv2[TA];
    __shared__ float  accA[TA];
    __shared__ int    idx_sh[TA];

    const int tid = threadIdx.x;

    // block -> (species, tile)
    int b = blockIdx.x;
    int s = -1, tile = 0, off = 0, cnt = 0, acc = 0;
    for (int q = 0; q < NSPEC; ++q) {
        int c = counts[q];
        int nb = (c + TA - 1) / TA;
        if (s < 0 && b < acc + nb) { s = q; tile = b - acc; off = offsets[q]; cnt = c; }
        acc += nb;
    }
    if (s < 0) return;

    const int base = tile * TA;
    int rem = cnt - base; if (rem > TA) rem = TA;

    if (tid < TA) {
        idx_sh[tid] = (tid < rem) ? order[off + base + tid] : -1;
        nrm[tid]  = 0.f;
        accA[tid] = 0.f;
    }
    lds_w[tid] = weights[s * NSUP + tid];
    __syncthreads();

    // stage A (64 rows x 32 float4), swizzled
    #pragma unroll
    for (int it = 0; it < (TA * 32) / 256; ++it) {
        int flat = it * 256 + tid;
        int row = flat >> 5;
        int c   = flat & 31;
        int a   = idx_sh[row];
        float4 v = make_float4(0.f, 0.f, 0.f, 0.f);
        if (a >= 0) v = *(const float4*)(ps + (size_t)a * KF + c * 4);
        ldsA[row * 32 + (c ^ ((row >> 2) & 7))] = v;
    }
    __syncthreads();

    // row norms^2 (4 threads per row)
    {
        int row = tid & 63, q = tid >> 6;
        int sw = (row >> 2) & 7;
        float sm = 0.f;
        #pragma unroll
        for (int c = q * 8; c < q * 8 + 8; ++c) {
            float4 v = ldsA[row * 32 + (c ^ sw)];
            sm += v.x * v.x + v.y * v.y + v.z * v.z + v.w * v.w;
        }
        atomicAdd(&nrm[row], sm);
    }
    __syncthreads();
    if (tid < TA) inv2[tid] = (nrm[tid] > 0.f) ? 1.0f / nrm[tid] : 0.f;

    const int tx = tid & 15, ty = tid >> 4;
    const int ta0 = tx * 4, tm0 = ty * 4;
    const int swA = tx & 7, swB = ty & 7;
    float peratom[4] = {0.f, 0.f, 0.f, 0.f};

    const float* sup_s = support + (size_t)s * NSUP * KF;

    for (int mt = 0; mt < NSUP / TM; ++mt) {
        __syncthreads();   // protect ldsS from previous iteration's readers
        #pragma unroll
        for (int it = 0; it < (TM * 32) / 256; ++it) {
            int flat = it * 256 + tid;
            int row = flat >> 5;
            int c   = flat & 31;
            float4 v = *(const float4*)(sup_s + (size_t)(mt * TM + row) * KF + c * 4);
            ldsS[row * 32 + (c ^ ((row >> 2) & 7))] = v;
        }
        __syncthreads();

        float dot[4][4];
        #pragma unroll
        for (int i = 0; i < 4; ++i)
            #pragma unroll
            for (int j = 0; j < 4; ++j) dot[i][j] = 0.f;

        #pragma unroll 8
        for (int c = 0; c < 32; ++c) {
            float4 av[4], bv[4];
            #pragma unroll
            for (int i = 0; i < 4; ++i) av[i] = ldsA[(ta0 + i) * 32 + (c ^ swA)];
            #pragma unroll
            for (int j = 0; j < 4; ++j) bv[j] = ldsS[(tm0 + j) * 32 + (c ^ swB)];
            #pragma unroll
            for (int i = 0; i < 4; ++i)
                #pragma unroll
                for (int j = 0; j < 4; ++j)
                    dot[i][j] += av[i].x * bv[j].x + av[i].y * bv[j].y
                               + av[i].z * bv[j].z + av[i].w * bv[j].w;
        }

        #pragma unroll
        for (int i = 0; i < 4; ++i) {
            float p = 0.f;
            #pragma unroll
            for (int j = 0; j < 4; ++j) {
                float d = dot[i][j];
                p += d * d * lds_w[mt * TM + tm0 + j];
            }
            peratom[i] += p;
        }
    }
    __syncthreads();

    #pragma unroll
    for (int i = 0; i < 4; ++i) atomicAdd(&accA[ta0 + i], peratom[i]);
    __syncthreads();

    if (tid < TA) {
        int a = idx_sh[tid];
        if (a >= 0) {
            float e = accA[tid] * inv2[tid];
            atomicAdd(&out[struct_ids[a]], e);
        }
    }
}

// ---------------- slow-but-correct fallback (ws too small) ----------------

__global__ void k_fallback(const float* __restrict__ ps, const float* __restrict__ support,
                           const float* __restrict__ weights, const int* __restrict__ species,
                           const int* __restrict__ struct_ids, float* __restrict__ out, int n)
{
    int gw = (blockIdx.x * blockDim.x + threadIdx.x) >> 6;
    int lane = threadIdx.x & 63;
    int nw = (gridDim.x * blockDim.x) >> 6;
    for (int atom = gw; atom < n; atom += nw) {
        const float* row = ps + (size_t)atom * KF;
        float x0 = row[lane], x1 = row[lane + 64];
        float nsum = x0 * x0 + x1 * x1;
        for (int o = 32; o; o >>= 1) nsum += __shfl_xor(nsum, o);
        float iv2 = 1.0f / nsum;
        int s = species[atom];
        const float* sup = support + (size_t)s * NSUP * KF;
        const float* w = weights + (size_t)s * NSUP;
        float e = 0.f;
        for (int mm = 0; mm < 4; ++mm) {
            int m = lane + mm * 64;
            const float* srow = sup + (size_t)m * KF;
            float d = 0.f;
            for (int k = 0; k < KF; ++k) d += row[k] * srow[k];
            e += d * d * w[m];
        }
        for (int o = 32; o; o >>= 1) e += __shfl_xor(e, o);
        if (lane == 0) atomicAdd(&out[struct_ids[atom]], e * iv2);
    }
}

// ---------------- launch ----------------

extern "C" void kernel_launch(void* const* d_in, const int* in_sizes, int n_in,
                              void* d_out, int out_size, void* d_ws, size_t ws_size,
                              hipStream_t stream)
{
    const float* ps       = (const float*)d_in[0];
    const float* support  = (const float*)d_in[1];
    const float* weights  = (const float*)d_in[2];
    const int*   species  = (const int*)d_in[3];
    const int*   sids     = (const int*)d_in[4];
    float* out = (float*)d_out;
    const int n = in_sizes[0] / KF;

    hipMemsetAsync(d_out, 0, (size_t)out_size * sizeof(float), stream);

    const size_t need = 64 + (size_t)n * sizeof(int);
    if (ws_size < need) {
        k_fallback<<<2048, 256, 0, stream>>>(ps, support, weights, species, sids, out, n);
        return;
    }

    int* ws      = (int*)d_ws;
    int* counts  = ws;        // 4
    int* offsets = ws + 4;    // 4
    int* cursors = ws + 8;    // 4
    int* order   = ws + 16;

    hipMemsetAsync(counts, 0, 16, stream);
    k_count<<<512, 256, 0, stream>>>(species, n, counts);
    k_scan<<<1, 64, 0, stream>>>(ws);
    k_scatter<<<(n + 255) / 256, 256, 0, stream>>>(species, n, cursors, order);

    int nb = (n + TA - 1) / TA + NSPEC;  // + padding for per-species ceil
    k_main<<<nb, 256, 0, stream>>>(ps, support, weights, sids, out, counts, offsets, order);
}

// Round 2
// 287.527 us; speedup vs baseline: 2.5634x; 2.5634x over previous
//
#include <hip/hip_runtime.h>

#define KF 128        // feature dim
#define NSUP 256      // support points per species
#define NSPEC 4
#define TA 64         // atom tile per block

typedef __bf16 bf16x8 __attribute__((ext_vector_type(8)));
typedef __bf16 bf16x4 __attribute__((ext_vector_type(4)));
typedef float  f32x4  __attribute__((ext_vector_type(4)));

// ---------------- species bucketing ----------------

__global__ void k_count(const int* __restrict__ sp, int n, int* __restrict__ counts) {
    __shared__ int h[NSPEC];
    if (threadIdx.x < NSPEC) h[threadIdx.x] = 0;
    __syncthreads();
    for (int i = blockIdx.x * blockDim.x + threadIdx.x; i < n; i += gridDim.x * blockDim.x)
        atomicAdd(&h[sp[i]], 1);
    __syncthreads();
    if (threadIdx.x < NSPEC) atomicAdd(&counts[threadIdx.x], h[threadIdx.x]);
}

__global__ void k_scan(int* ws) {
    if (threadIdx.x == 0 && blockIdx.x == 0) {
        int acc = 0;
        for (int q = 0; q < NSPEC; ++q) { ws[4 + q] = acc; ws[8 + q] = acc; acc += ws[q]; }
    }
}

__global__ void k_scatter(const int* __restrict__ sp, int n,
                          int* __restrict__ cursors, int* __restrict__ order) {
    __shared__ int lh[NSPEC];
    __shared__ int base[NSPEC];
    if (threadIdx.x < NSPEC) lh[threadIdx.x] = 0;
    __syncthreads();
    int i = blockIdx.x * blockDim.x + threadIdx.x;
    int s = (i < n) ? sp[i] : -1;
    int local = 0;
    if (s >= 0) local = atomicAdd(&lh[s], 1);
    __syncthreads();
    if (threadIdx.x < NSPEC) base[threadIdx.x] = atomicAdd(&cursors[threadIdx.x], lh[threadIdx.x]);
    __syncthreads();
    if (s >= 0) order[base[s] + local] = i;
}

// ---------------- support -> fragment-major bf16 ----------------
// Fragment order: [species][coltile 0..15][kstep 0..3][lane 0..63][8 bf16]
// Lane l supplies B col = ct*16 + (l&15), k = kk*32 + (l>>4)*8 .. +7.

__global__ void k_prep_support(const float* __restrict__ sup, __bf16* __restrict__ outb) {
    int t = blockIdx.x * blockDim.x + threadIdx.x;
    if (t >= NSPEC * 16 * 4 * 64) return;
    int lane = t & 63;
    int kk   = (t >> 6) & 3;
    int ct   = (t >> 8) & 15;
    int s    = t >> 12;
    int m  = ct * 16 + (lane & 15);
    int k0 = kk * 32 + (lane >> 4) * 8;
    const float* src = sup + ((size_t)(s * NSUP + m)) * KF + k0;
    bf16x8 v;
    #pragma unroll
    for (int j = 0; j < 8; ++j) v[j] = (__bf16)src[j];
    *(bf16x8*)(outb + (size_t)t * 8) = v;
}

// ---------------- main fused MFMA kernel ----------------

__global__ __launch_bounds__(256, 3) void k_main(
    const float* __restrict__ ps,
    const __bf16* __restrict__ sup_frag,
    const float* __restrict__ weights,
    const int* __restrict__ struct_ids,
    float* __restrict__ out,
    const int* __restrict__ counts,
    const int* __restrict__ offsets,
    const int* __restrict__ order)
{
    __shared__ __align__(16) char ldsA[TA * 256];  // 64 rows x 128 bf16, XOR-swizzled
    __shared__ float nrm[TA];
    __shared__ float accW[4][TA];
    __shared__ int   idx_sh[TA];

    const int tid = threadIdx.x;

    // block -> (species, tile)
    int b = blockIdx.x;
    int s = -1, tile = 0, off = 0, cnt = 0, acc0 = 0;
    for (int q = 0; q < NSPEC; ++q) {
        int c = counts[q];
        int nb = (c + TA - 1) / TA;
        if (s < 0 && b < acc0 + nb) { s = q; tile = b - acc0; off = offsets[q]; cnt = c; }
        acc0 += nb;
    }
    if (s < 0) return;

    const int base = tile * TA;
    int rem = cnt - base; if (rem > TA) rem = TA;
    if (tid < TA) idx_sh[tid] = (tid < rem) ? order[off + base + tid] : -1;
    __syncthreads();

    // stage A (fp32 -> bf16, swizzled) + row norms^2 from fp32
    #pragma unroll
    for (int it = 0; it < 8; ++it) {
        int flat = it * 256 + tid;
        int row = flat >> 5, c = flat & 31;   // 32 float4 per row
        int a = idx_sh[row];
        float4 v = make_float4(0.f, 0.f, 0.f, 0.f);
        if (a >= 0) v = *(const float4*)(ps + (size_t)a * KF + c * 4);
        bf16x4 bv;
        bv[0] = (__bf16)v.x; bv[1] = (__bf16)v.y; bv[2] = (__bf16)v.z; bv[3] = (__bf16)v.w;
        *(bf16x4*)(ldsA + row * 256 + ((c * 8) ^ ((row & 7) << 4))) = bv;
        float sm = v.x * v.x + v.y * v.y + v.z * v.z + v.w * v.w;
        #pragma unroll
        for (int m = 1; m < 32; m <<= 1) sm += __shfl_xor(sm, m, 32);
        if ((tid & 31) == 0) nrm[row] = sm;   // unique (it, half-wave) -> row
    }
    __syncthreads();

    const int lane = tid & 63, w = tid >> 6;
    const int lrow = lane & 15, lk = lane >> 4;

    float wreg[4];
    #pragma unroll
    for (int ct = 0; ct < 4; ++ct)
        wreg[ct] = weights[s * NSUP + (w * 4 + ct) * 16 + lrow];

    f32x4 acc[4][4];
    #pragma unroll
    for (int i = 0; i < 4; ++i)
        #pragma unroll
        for (int j = 0; j < 4; ++j) acc[i][j] = (f32x4){0.f, 0.f, 0.f, 0.f};

    const __bf16* bsup = sup_frag + (size_t)s * (16 * 4 * 64 * 8);

    #pragma unroll
    for (int kk = 0; kk < 4; ++kk) {
        bf16x8 afr[4];
        #pragma unroll
        for (int rt = 0; rt < 4; ++rt) {
            int row = rt * 16 + lrow;
            afr[rt] = *(const bf16x8*)(ldsA + row * 256 + ((kk * 64 + lk * 16) ^ ((row & 7) << 4)));
        }
        #pragma unroll
        for (int ct = 0; ct < 4; ++ct) {
            int ctg = w * 4 + ct;
            bf16x8 bfr = *(const bf16x8*)(bsup + ((size_t)(ctg * 4 + kk) * 64 + lane) * 8);
            #pragma unroll
            for (int rt = 0; rt < 4; ++rt)
                acc[rt][ct] = __builtin_amdgcn_mfma_f32_16x16x32_bf16(afr[rt], bfr, acc[rt][ct], 0, 0, 0);
        }
    }

    // epilogue: e_i partial = sum_m d^2 * w ; reduce over the 16 col-lanes
    #pragma unroll
    for (int rt = 0; rt < 4; ++rt) {
        float pj[4] = {0.f, 0.f, 0.f, 0.f};
        #pragma unroll
        for (int ct = 0; ct < 4; ++ct)
            #pragma unroll
            for (int j = 0; j < 4; ++j) {
                float d = acc[rt][ct][j];
                pj[j] += d * d * wreg[ct];
            }
        #pragma unroll
        for (int j = 0; j < 4; ++j) {
            float v = pj[j];
            #pragma unroll
            for (int m = 1; m < 16; m <<= 1) v += __shfl_xor(v, m, 16);
            if (lrow == 0) accW[w][rt * 16 + lk * 4 + j] = v;
        }
    }
    __syncthreads();

    if (tid < TA) {
        int a = idx_sh[tid];
        if (a >= 0) {
            float nn = nrm[tid];
            float e = accW[0][tid] + accW[1][tid] + accW[2][tid] + accW[3][tid];
            e = (nn > 0.f) ? e / nn : 0.f;
            atomicAdd(&out[struct_ids[a]], e);
        }
    }
}

// ---------------- slow-but-correct fallback (ws too small) ----------------

__global__ void k_fallback(const float* __restrict__ ps, const float* __restrict__ support,
                           const float* __restrict__ weights, const int* __restrict__ species,
                           const int* __restrict__ struct_ids, float* __restrict__ out, int n)
{
    int gw = (blockIdx.x * blockDim.x + threadIdx.x) >> 6;
    int lane = threadIdx.x & 63;
    int nw = (gridDim.x * blockDim.x) >> 6;
    for (int atom = gw; atom < n; atom += nw) {
        const float* row = ps + (size_t)atom * KF;
        float x0 = row[lane], x1 = row[lane + 64];
        float nsum = x0 * x0 + x1 * x1;
        for (int o = 32; o; o >>= 1) nsum += __shfl_xor(nsum, o);
        float iv2 = 1.0f / nsum;
        int s = species[atom];
        const float* sup = support + (size_t)s * NSUP * KF;
        const float* w = weights + (size_t)s * NSUP;
        float e = 0.f;
        for (int mm = 0; mm < 4; ++mm) {
            int m = lane + mm * 64;
            const float* srow = sup + (size_t)m * KF;
            float d = 0.f;
            for (int k = 0; k < KF; ++k) d += row[k] * srow[k];
            e += d * d * w[m];
        }
        for (int o = 32; o; o >>= 1) e += __shfl_xor(e, o);
        if (lane == 0) atomicAdd(&out[struct_ids[atom]], e * iv2);
    }
}

// ---------------- launch ----------------

extern "C" void kernel_launch(void* const* d_in, const int* in_sizes, int n_in,
                              void* d_out, int out_size, void* d_ws, size_t ws_size,
                              hipStream_t stream)
{
    const float* ps       = (const float*)d_in[0];
    const float* support  = (const float*)d_in[1];
    const float* weights  = (const float*)d_in[2];
    const int*   species  = (const int*)d_in[3];
    const int*   sids     = (const int*)d_in[4];
    float* out = (float*)d_out;
    const int n = in_sizes[0] / KF;

    hipMemsetAsync(d_out, 0, (size_t)out_size * sizeof(float), stream);

    const size_t frag_bytes = (size_t)NSPEC * 16 * 4 * 64 * 8 * sizeof(__bf16);  // 256 KB
    size_t order_end = 64 + (size_t)n * sizeof(int);
    size_t frag_off  = (order_end + 15) & ~(size_t)15;
    const size_t need = frag_off + frag_bytes;
    if (ws_size < need) {
        k_fallback<<<2048, 256, 0, stream>>>(ps, support, weights, species, sids, out, n);
        return;
    }

    int* ws      = (int*)d_ws;
    int* counts  = ws;        // 4
    int* offsets = ws + 4;    // 4
    int* cursors = ws + 8;    // 4
    int* order   = ws + 16;
    __bf16* sup_frag = (__bf16*)((char*)d_ws + frag_off);

    hipMemsetAsync(counts, 0, 16, stream);
    k_count<<<512, 256, 0, stream>>>(species, n, counts);
    k_scan<<<1, 64, 0, stream>>>(ws);
    k_scatter<<<(n + 255) / 256, 256, 0, stream>>>(species, n, cursors, order);
    k_prep_support<<<(NSPEC * 16 * 4 * 64 + 255) / 256, 256, 0, stream>>>(support, sup_frag);

    int nb = (n + TA - 1) / TA + NSPEC;
    k_main<<<nb, 256, 0, stream>>>(ps, sup_frag, weights, sids, out,
                                   counts, offsets, order);
}